// Round 1
// baseline (524.599 us; speedup 1.0000x reference)
//
#include <hip/hip_runtime.h>
#include <hip/hip_bf16.h>
#include <stdint.h>

typedef __bf16 bf16_t;
typedef __bf16 bf16x8 __attribute__((ext_vector_type(8)));
typedef float f32x4 __attribute__((ext_vector_type(4)));

#define M_ROWS 8192
#define N_COLS 4096
#define K_DIM  4096
#define KEXT   64
#define BM 128
#define BN 128
#define BK 64
#define NKT (K_DIM / BK)

// ws layout
#define XBF_BYTES (67108864ull)   // 8192*4096*2
#define WBF_BYTES (33554432ull)   // 4096*4096*2
#define LOW_BYTES (1048576ull)    // 8192*64*2
#define LBT_BYTES (2097152ull)    // 4*4096*64*2

__device__ __forceinline__ void gload16(const void* g, void* l) {
    __builtin_amdgcn_global_load_lds(
        (const __attribute__((address_space(1))) unsigned int*)g,
        (__attribute__((address_space(3))) unsigned int*)l, 16, 0, 0);
}

// ---------------------------------------------------------------------------
// W f32 -> bf16
__global__ __launch_bounds__(256) void convert_w_kernel(
    const float* __restrict__ src, bf16_t* __restrict__ dst)
{
    const long long n8 = (long long)(N_COLS) * K_DIM / 8;  // 2097152
    const long long stride = (long long)gridDim.x * blockDim.x;
    for (long long i = (long long)blockIdx.x * blockDim.x + threadIdx.x; i < n8; i += stride) {
        const f32x4* s = (const f32x4*)(src + i * 8);
        const f32x4 a = s[0], b = s[1];
        bf16x8 v;
        v[0]=(bf16_t)a[0]; v[1]=(bf16_t)a[1]; v[2]=(bf16_t)a[2]; v[3]=(bf16_t)a[3];
        v[4]=(bf16_t)b[0]; v[5]=(bf16_t)b[1]; v[6]=(bf16_t)b[2]; v[7]=(bf16_t)b[3];
        *(bf16x8*)(dst + i * 8) = v;
    }
}

// ---------------------------------------------------------------------------
// lBt[b][n][r] = bf16(2.0f * lora_B[b][r][n]), r<16; cols 16..63 pre-zeroed.
__global__ __launch_bounds__(256) void make_lbt_kernel(
    const float* __restrict__ lB, bf16_t* __restrict__ lBt)
{
    const int idx = blockIdx.x * 256 + threadIdx.x;   // 0..16383
    const int b = idx >> 12, n = idx & 4095;
    const float* src = lB + (size_t)b * (16 * N_COLS) + n;
    bf16_t* dst = lBt + ((size_t)b * N_COLS + n) * KEXT;
    #pragma unroll
    for (int r = 0; r < 16; ++r)
        dst[r] = (bf16_t)(2.0f * src[(size_t)r * N_COLS]);
}

// ---------------------------------------------------------------------------
// Fused: Xbf = bf16(x), low[m][r] = sum_k x[m][k]*lora_A[b][k][r]  (fp32 acc)
// Block: 16 rows; thread = (rg = tid>>6 -> 4 rows) x (lane -> k-subset).
__global__ __launch_bounds__(256) void low_kernel(
    const float* __restrict__ x, const float* __restrict__ lA,
    bf16_t* __restrict__ Xbf, bf16_t* __restrict__ lowbf)
{
    const int tid  = threadIdx.x;
    const int m0   = blockIdx.x * 16;
    const int batch = m0 >> 11;
    const int rg   = tid >> 6;
    const int lane = tid & 63;
    const float* lAb = lA + (size_t)batch * (K_DIM * 16);

    f32x4 acc4[4][4];
    #pragma unroll
    for (int i = 0; i < 4; ++i)
        #pragma unroll
        for (int j = 0; j < 4; ++j)
            acc4[i][j] = (f32x4)0.0f;

    #pragma unroll 1
    for (int kc = 0; kc < 8; ++kc) {
        const int k0 = kc * 512 + lane * 8;
        float xs[4][8];
        #pragma unroll
        for (int rr = 0; rr < 4; ++rr) {
            const int m = m0 + rg * 4 + rr;
            const float* xp = x + (size_t)m * K_DIM + k0;
            const f32x4 a = *(const f32x4*)xp;
            const f32x4 b = *(const f32x4*)(xp + 4);
            bf16x8 v;
            v[0]=(bf16_t)a[0]; v[1]=(bf16_t)a[1]; v[2]=(bf16_t)a[2]; v[3]=(bf16_t)a[3];
            v[4]=(bf16_t)b[0]; v[5]=(bf16_t)b[1]; v[6]=(bf16_t)b[2]; v[7]=(bf16_t)b[3];
            *(bf16x8*)(Xbf + (size_t)m * K_DIM + k0) = v;
            xs[rr][0]=a[0]; xs[rr][1]=a[1]; xs[rr][2]=a[2]; xs[rr][3]=a[3];
            xs[rr][4]=b[0]; xs[rr][5]=b[1]; xs[rr][6]=b[2]; xs[rr][7]=b[3];
        }
        #pragma unroll
        for (int j = 0; j < 8; ++j) {
            const f32x4* lr = (const f32x4*)(lAb + (size_t)(k0 + j) * 16);
            const f32x4 l0 = lr[0], l1 = lr[1], l2 = lr[2], l3 = lr[3];
            #pragma unroll
            for (int rr = 0; rr < 4; ++rr) {
                const float xv = xs[rr][j];
                acc4[rr][0] += xv * l0;
                acc4[rr][1] += xv * l1;
                acc4[rr][2] += xv * l2;
                acc4[rr][3] += xv * l3;
            }
        }
    }

    // full-wave butterfly reduce (all 64 lanes of a wave share the same rg)
    #pragma unroll
    for (int off = 32; off >= 1; off >>= 1) {
        #pragma unroll
        for (int rr = 0; rr < 4; ++rr)
            #pragma unroll
            for (int g = 0; g < 4; ++g)
                #pragma unroll
                for (int q = 0; q < 4; ++q)
                    acc4[rr][g][q] += __shfl_xor(acc4[rr][g][q], off, 64);
    }

    // lane l writes low[m0 + rg*4 + (l>>4)][l&15]; static-index select (rule #20)
    const int rr_w = lane >> 4, rw = lane & 15;
    float outv = 0.0f;
    #pragma unroll
    for (int rr = 0; rr < 4; ++rr)
        #pragma unroll
        for (int g = 0; g < 4; ++g)
            #pragma unroll
            for (int q = 0; q < 4; ++q)
                if (rr == rr_w && (g * 4 + q) == rw) outv = acc4[rr][g][q];
    lowbf[(size_t)(m0 + rg * 4 + rr_w) * KEXT + rw] = (bf16_t)outv;
}

// ---------------------------------------------------------------------------
// Main augmented GEMM: out = Xbf @ Wbf^T (+ext step: low @ lBt^T) + bias
// m97 structure: 128x128 tile, BK=64, 4 waves (2x2), 16x16x32 bf16 MFMA.
__global__ __launch_bounds__(256) void gemm_lora_kernel(
    const bf16_t* __restrict__ Xbf, const bf16_t* __restrict__ Wbf,
    const bf16_t* __restrict__ lowbf, const bf16_t* __restrict__ lBt,
    const float* __restrict__ bias, float* __restrict__ out)
{
    __shared__ __align__(16) bf16_t As[BM * BK];
    __shared__ __align__(16) bf16_t Bs[BN * BK];

    // XCD-aware swizzle (grid = 2048, divisible by 8 -> bijective)
    int wg = blockIdx.x;
    const int cpx = gridDim.x >> 3;
    wg = (wg & 7) * cpx + (wg >> 3);

    const int nbn  = N_COLS / BN;          // 32
    const int brow = (wg / nbn) * BM;
    const int bcol = (wg % nbn) * BN;
    const int batch = brow >> 11;          // 2048 rows per batch, 128 | 2048

    const int tid  = threadIdx.x;
    const int lane = tid & 63;
    const int w    = tid >> 6;
    const int wr   = w >> 1, wc = w & 1;

    // staging: issue i covers tile rows w*32 + i*8 + lane/8, col (lane%8)*8
    const int ldRow = w * 32 + (lane >> 3);
    const int ldCol = (lane & 7) * 8;

    const bf16_t* aBase = Xbf + (size_t)(brow + ldRow) * K_DIM + ldCol;
    const bf16_t* bBase = Wbf + (size_t)(bcol + ldRow) * K_DIM + ldCol;
    const bf16_t* aExt  = lowbf + (size_t)(brow + ldRow) * KEXT + ldCol;
    const bf16_t* bExt  = lBt + ((size_t)batch * N_COLS + bcol + ldRow) * KEXT + ldCol;

    bf16_t* lA = As + (size_t)w * 2048;    // wave-uniform LDS base
    bf16_t* lB = Bs + (size_t)w * 2048;

    f32x4 acc[4][4];
    #pragma unroll
    for (int i = 0; i < 4; ++i)
        #pragma unroll
        for (int j = 0; j < 4; ++j)
            acc[i][j] = (f32x4)0.0f;

    const int arow0 = (wr * 64 + (lane & 15)) * BK;
    const int brow0 = (wc * 64 + (lane & 15)) * BK;
    const int kbase = (lane >> 4) * 8;

    for (int kt = 0; kt <= NKT; ++kt) {
        __syncthreads();
        if (kt < NKT) {
            const bf16_t* ga = aBase + kt * BK;
            const bf16_t* gb = bBase + kt * BK;
            #pragma unroll
            for (int i = 0; i < 4; ++i) {
                gload16(ga + (size_t)i * 8 * K_DIM, lA + i * 512);
                gload16(gb + (size_t)i * 8 * K_DIM, lB + i * 512);
            }
        } else {
            #pragma unroll
            for (int i = 0; i < 4; ++i) {
                gload16(aExt + i * 8 * KEXT, lA + i * 512);
                gload16(bExt + i * 8 * KEXT, lB + i * 512);
            }
        }
        __syncthreads();
        #pragma unroll
        for (int kk = 0; kk < 2; ++kk) {
            const int ko = kk * 32 + kbase;
            bf16x8 af[4], bfr[4];
            #pragma unroll
            for (int mi = 0; mi < 4; ++mi)
                af[mi] = *(const bf16x8*)(As + arow0 + mi * 16 * BK + ko);
            #pragma unroll
            for (int ni = 0; ni < 4; ++ni)
                bfr[ni] = *(const bf16x8*)(Bs + brow0 + ni * 16 * BK + ko);
            #pragma unroll
            for (int mi = 0; mi < 4; ++mi)
                #pragma unroll
                for (int ni = 0; ni < 4; ++ni)
                    acc[mi][ni] = __builtin_amdgcn_mfma_f32_16x16x32_bf16(
                        af[mi], bfr[ni], acc[mi][ni], 0, 0, 0);
        }
    }

    // epilogue: bias add + store (C/D layout: col = lane&15, row = (lane>>4)*4 + r)
    float bv[4];
    #pragma unroll
    for (int ni = 0; ni < 4; ++ni)
        bv[ni] = bias[bcol + wc * 64 + ni * 16 + (lane & 15)];
    const int r0 = (lane >> 4) * 4;
    #pragma unroll
    for (int mi = 0; mi < 4; ++mi) {
        const int row = brow + wr * 64 + mi * 16 + r0;
        #pragma unroll
        for (int ni = 0; ni < 4; ++ni) {
            const int col = bcol + wc * 64 + ni * 16 + (lane & 15);
            float* op = out + (size_t)row * N_COLS + col;
            #pragma unroll
            for (int r = 0; r < 4; ++r)
                op[(size_t)r * N_COLS] = acc[mi][ni][r] + bv[ni];
        }
    }
}

// ---------------------------------------------------------------------------
extern "C" void kernel_launch(void* const* d_in, const int* in_sizes, int n_in,
                              void* d_out, int out_size, void* d_ws, size_t ws_size,
                              hipStream_t stream) {
    const float* x      = (const float*)d_in[0];
    const float* weight = (const float*)d_in[1];
    const float* bias   = (const float*)d_in[2];
    const float* lora_A = (const float*)d_in[3];
    const float* lora_B = (const float*)d_in[4];
    float* out = (float*)d_out;

    if (ws_size < XBF_BYTES + WBF_BYTES + LOW_BYTES + LBT_BYTES) return;

    char* ws = (char*)d_ws;
    bf16_t* Xbf  = (bf16_t*)ws;
    bf16_t* Wbf  = (bf16_t*)(ws + XBF_BYTES);
    bf16_t* lowb = (bf16_t*)(ws + XBF_BYTES + WBF_BYTES);
    bf16_t* lBt  = (bf16_t*)(ws + XBF_BYTES + WBF_BYTES + LOW_BYTES);

    // zero the padded low-rank buffers (cols 16..63 must be 0 every call)
    hipMemsetAsync(lowb, 0, LOW_BYTES + LBT_BYTES, stream);

    convert_w_kernel<<<2048, 256, 0, stream>>>(weight, Wbf);
    make_lbt_kernel<<<64, 256, 0, stream>>>(lora_B, lBt);
    low_kernel<<<512, 256, 0, stream>>>(x, lora_A, Xbf, lowb);
    gemm_lora_kernel<<<2048, 256, 0, stream>>>(Xbf, Wbf, lowb, lBt, bias, out);
}

// Round 3
// 386.071 us; speedup vs baseline: 1.3588x; 1.3588x over previous
//
#include <hip/hip_runtime.h>
#include <hip/hip_bf16.h>
#include <stdint.h>

typedef __bf16 bf16_t;
typedef __bf16 bf16x8 __attribute__((ext_vector_type(8)));
typedef float f32x4 __attribute__((ext_vector_type(4)));

#define M_ROWS 8192
#define N_COLS 4096
#define K_DIM  4096
#define KEXT   64
#define BM 256
#define BN 256
#define BK 64
#define NT 65   // 64 main K-tiles + 1 LoRA extension tile

// ws layout
#define XBF_BYTES (67108864ull)   // 8192*4096*2
#define WBF_BYTES (33554432ull)   // 4096*4096*2
#define LOW_BYTES (1048576ull)    // 8192*64*2
#define LBT_BYTES (2097152ull)    // 4*4096*64*2

__device__ __forceinline__ void gload16(const void* g, void* l) {
    __builtin_amdgcn_global_load_lds(
        (const __attribute__((address_space(1))) unsigned int*)g,
        (__attribute__((address_space(3))) unsigned int*)l, 16, 0, 0);
}

// ---------------------------------------------------------------------------
// W f32 -> bf16
__global__ __launch_bounds__(256) void convert_w_kernel(
    const float* __restrict__ src, bf16_t* __restrict__ dst)
{
    const long long n8 = (long long)(N_COLS) * K_DIM / 8;
    const long long stride = (long long)gridDim.x * blockDim.x;
    for (long long i = (long long)blockIdx.x * blockDim.x + threadIdx.x; i < n8; i += stride) {
        const f32x4* s = (const f32x4*)(src + i * 8);
        const f32x4 a = s[0], b = s[1];
        bf16x8 v;
        v[0]=(bf16_t)a[0]; v[1]=(bf16_t)a[1]; v[2]=(bf16_t)a[2]; v[3]=(bf16_t)a[3];
        v[4]=(bf16_t)b[0]; v[5]=(bf16_t)b[1]; v[6]=(bf16_t)b[2]; v[7]=(bf16_t)b[3];
        *(bf16x8*)(dst + i * 8) = v;
    }
}

// ---------------------------------------------------------------------------
// lBt[b][n][r] = bf16(2.0f * lora_B[b][r][n]), r<16; cols 16..63 pre-zeroed.
__global__ __launch_bounds__(256) void make_lbt_kernel(
    const float* __restrict__ lB, bf16_t* __restrict__ lBt)
{
    const int idx = blockIdx.x * 256 + threadIdx.x;
    const int b = idx >> 12, n = idx & 4095;
    const float* src = lB + (size_t)b * (16 * N_COLS) + n;
    bf16_t* dst = lBt + ((size_t)b * N_COLS + n) * KEXT;
    #pragma unroll
    for (int r = 0; r < 16; ++r)
        dst[r] = (bf16_t)(2.0f * src[(size_t)r * N_COLS]);
}

// ---------------------------------------------------------------------------
// Fused: Xbf = bf16(x), low[m][r] = sum_k x[m][k]*lora_A[b][k][r]  (fp32 acc)
__global__ __launch_bounds__(256) void low_kernel(
    const float* __restrict__ x, const float* __restrict__ lA,
    bf16_t* __restrict__ Xbf, bf16_t* __restrict__ lowbf)
{
    const int tid  = threadIdx.x;
    const int m0   = blockIdx.x * 16;
    const int batch = m0 >> 11;
    const int rg   = tid >> 6;
    const int lane = tid & 63;
    const float* lAb = lA + (size_t)batch * (K_DIM * 16);

    f32x4 acc4[4][4];
    #pragma unroll
    for (int i = 0; i < 4; ++i)
        #pragma unroll
        for (int j = 0; j < 4; ++j)
            acc4[i][j] = (f32x4)0.0f;

    #pragma unroll 1
    for (int kc = 0; kc < 8; ++kc) {
        const int k0 = kc * 512 + lane * 8;
        float xs[4][8];
        #pragma unroll
        for (int rr = 0; rr < 4; ++rr) {
            const int m = m0 + rg * 4 + rr;
            const float* xp = x + (size_t)m * K_DIM + k0;
            const f32x4 a = *(const f32x4*)xp;
            const f32x4 b = *(const f32x4*)(xp + 4);
            bf16x8 v;
            v[0]=(bf16_t)a[0]; v[1]=(bf16_t)a[1]; v[2]=(bf16_t)a[2]; v[3]=(bf16_t)a[3];
            v[4]=(bf16_t)b[0]; v[5]=(bf16_t)b[1]; v[6]=(bf16_t)b[2]; v[7]=(bf16_t)b[3];
            *(bf16x8*)(Xbf + (size_t)m * K_DIM + k0) = v;
            xs[rr][0]=a[0]; xs[rr][1]=a[1]; xs[rr][2]=a[2]; xs[rr][3]=a[3];
            xs[rr][4]=b[0]; xs[rr][5]=b[1]; xs[rr][6]=b[2]; xs[rr][7]=b[3];
        }
        #pragma unroll
        for (int j = 0; j < 8; ++j) {
            const f32x4* lr = (const f32x4*)(lAb + (size_t)(k0 + j) * 16);
            const f32x4 l0 = lr[0], l1 = lr[1], l2 = lr[2], l3 = lr[3];
            #pragma unroll
            for (int rr = 0; rr < 4; ++rr) {
                const float xv = xs[rr][j];
                acc4[rr][0] += xv * l0;
                acc4[rr][1] += xv * l1;
                acc4[rr][2] += xv * l2;
                acc4[rr][3] += xv * l3;
            }
        }
    }

    #pragma unroll
    for (int off = 32; off >= 1; off >>= 1) {
        #pragma unroll
        for (int rr = 0; rr < 4; ++rr)
            #pragma unroll
            for (int g = 0; g < 4; ++g)
                #pragma unroll
                for (int q = 0; q < 4; ++q)
                    acc4[rr][g][q] += __shfl_xor(acc4[rr][g][q], off, 64);
    }

    const int rr_w = lane >> 4, rw = lane & 15;
    float outv = 0.0f;
    #pragma unroll
    for (int rr = 0; rr < 4; ++rr)
        #pragma unroll
        for (int g = 0; g < 4; ++g)
            #pragma unroll
            for (int q = 0; q < 4; ++q)
                if (rr == rr_w && (g * 4 + q) == rw) outv = acc4[rr][g][q];
    lowbf[(size_t)(m0 + rg * 4 + rr_w) * KEXT + rw] = (bf16_t)outv;
}

// ---------------------------------------------------------------------------
// 256x256 8-phase GEMM (T1+T2+T3+T4+T5), K = 64 main tiles + 1 LoRA ext tile.
// LDS: [2 dbuf][A 32K | B 32K] = 128 KiB. Flat [256 rows][128B] tiles with
// byte-swizzle b ^= ((row&7)<<4) applied on pre-swizzled global source
// (linear global_load_lds dest) and on ds_read addresses.
//
// WAR map (why stages sit where they do):
//   A rows {0..63,128..191} read in ph1 -> restaged (tile t+2, cur buf) in ph2
//   A rows {64..127,192..255} read in ph3 -> restaged in ph4
//   B rows 0..127 read by ph1+ph2 -> restaged in ph3
//   B rows 128..255 (tile t+1, other buf) last read iter t-1 ph2 -> staged ph1
__global__ __launch_bounds__(512, 1) void gemm_lora_kernel(
    const bf16_t* __restrict__ Xbf, const bf16_t* __restrict__ Wbf,
    const bf16_t* __restrict__ lowbf, const bf16_t* __restrict__ lBt,
    const float* __restrict__ bias, float* __restrict__ out)
{
    __shared__ __align__(16) char lds[131072];

    // XCD-aware bijective swizzle (512 % 8 == 0)
    int wg = blockIdx.x;
    const int cpx = gridDim.x >> 3;
    wg = (wg & 7) * cpx + (wg >> 3);

    const int nbn  = N_COLS / BN;            // 16
    const int brow = (wg / nbn) * BM;
    const int bcol = (wg % nbn) * BN;
    const int batch = brow >> 11;            // 256 | 2048

    const int tid  = threadIdx.x;
    const int lane = tid & 63;
    const int w    = tid >> 6;
    const int wr   = w >> 2;                 // 0..1 -> M half (128 rows)
    const int wc   = w & 3;                  // 0..3 -> N quarter (64 cols)

    // ---- staging constants: one 64-row unit = 8192B = 512 thr x 16B.
    // thread covers row u*64 + (tid>>3), physical byte (tid&7)*16 of that row;
    // global source col = inverse-swizzled logical col (row&7 == srow&7).
    const int srow   = tid >> 3;                                   // 0..63
    const int bphys  = (tid & 7) * 16;
    const int colOff = (bphys ^ ((srow & 7) << 4)) >> 1;           // elems 0..63

    const bf16_t* aSrc = Xbf + (size_t)(brow + srow) * K_DIM + colOff;
    const bf16_t* bSrc = Wbf + (size_t)(bcol + srow) * K_DIM + colOff;
    const bf16_t* aExt = lowbf + (size_t)(brow + srow) * KEXT + colOff;
    const bf16_t* bExt = lBt + ((size_t)batch * N_COLS + bcol + srow) * KEXT + colOff;

    // stage one 64-row A unit u (rows u*64 .. u*64+63) of K-tile tau
    auto stageAu = [&](int tau, int u) {
        char* dst = lds + (tau & 1) * 65536 + u * 8192 + tid * 16;
        if (tau < NT - 1) gload16(aSrc + (size_t)(u * 64) * K_DIM + tau * BK, dst);
        else              gload16(aExt + (size_t)(u * 64) * KEXT, dst);
    };
    // stage B half-tile h (rows h*128 .. h*128+127) of K-tile tau (2 loads)
    auto stageBh = [&](int tau, int h) {
        char* dst = lds + (tau & 1) * 65536 + 32768 + h * 16384 + tid * 16;
        if (tau < NT - 1) {
            const bf16_t* s = bSrc + (size_t)(h * 128) * K_DIM + tau * BK;
            gload16(s, dst);
            gload16(s + (size_t)64 * K_DIM, dst + 8192);
        } else {
            const bf16_t* s = bExt + (size_t)(h * 128) * KEXT;
            gload16(s, dst);
            gload16(s + 64 * KEXT, dst + 8192);
        }
    };

    // ---- fragment-read constants
    const int aRowB = (wr * 128 + (lane & 15)) * 128;
    const int bRowB = (wc * 64 + (lane & 15)) * 128;
    const int swz[2] = { (((lane >> 4) * 16) ^ ((lane & 7) << 4)),
                         ((64 + (lane >> 4) * 16) ^ ((lane & 7) << 4)) };

    f32x4 acc[8][4];
    #pragma unroll
    for (int i = 0; i < 8; ++i)
        #pragma unroll
        for (int j = 0; j < 4; ++j)
            acc[i][j] = (f32x4)0.0f;

    bf16x8 aF[2][4], b0F[2][2], b1F[2][2];

    // ---- prologue: tile0 fully (8 loads) + tile1 {Au0,Au2,B0,Au1,Au3} (6)
    stageAu(0, 0); stageAu(0, 1); stageAu(0, 2); stageAu(0, 3);
    stageBh(0, 0); stageBh(0, 1);
    stageAu(1, 0); stageAu(1, 2); stageBh(1, 0); stageAu(1, 1); stageAu(1, 3);
    asm volatile("s_waitcnt vmcnt(6)" ::: "memory");   // tile 0 landed
    __builtin_amdgcn_s_barrier();

    #pragma unroll 1
    for (int t = 0; t < NT; ++t) {
        char* const Ab = lds + (t & 1) * 65536;
        char* const Bb = Ab + 32768;

        // ===== phase 1: quadrant (mh=0, nh=0); reads A rows {wr*128+0..63}, B0
        #pragma unroll
        for (int kk = 0; kk < 2; ++kk)
            #pragma unroll
            for (int mi = 0; mi < 4; ++mi)
                aF[kk][mi] = *(const bf16x8*)(Ab + aRowB + mi * 2048 + swz[kk]);
        #pragma unroll
        for (int kk = 0; kk < 2; ++kk)
            #pragma unroll
            for (int ni = 0; ni < 2; ++ni)
                b0F[kk][ni] = *(const bf16x8*)(Bb + bRowB + ni * 2048 + swz[kk]);
        if (t + 1 < NT) stageBh(t + 1, 1);       // other buffer
        __builtin_amdgcn_s_barrier();
        asm volatile("s_waitcnt lgkmcnt(0)" ::: "memory");
        __builtin_amdgcn_s_setprio(1);
        #pragma unroll
        for (int kk = 0; kk < 2; ++kk)
            #pragma unroll
            for (int mi = 0; mi < 4; ++mi)
                #pragma unroll
                for (int ni = 0; ni < 2; ++ni)
                    acc[mi][ni] = __builtin_amdgcn_mfma_f32_16x16x32_bf16(
                        aF[kk][mi], b0F[kk][ni], acc[mi][ni], 0, 0, 0);
        __builtin_amdgcn_s_setprio(0);
        __builtin_amdgcn_s_barrier();

        // ===== phase 2: quadrant (0,1); reads B1; restage A units 0,2 (dead)
        #pragma unroll
        for (int kk = 0; kk < 2; ++kk)
            #pragma unroll
            for (int ni = 0; ni < 2; ++ni)
                b1F[kk][ni] = *(const bf16x8*)(Bb + bRowB + 4096 + ni * 2048 + swz[kk]);
        if (t + 2 < NT) { stageAu(t + 2, 0); stageAu(t + 2, 2); }
        __builtin_amdgcn_s_barrier();
        asm volatile("s_waitcnt lgkmcnt(0)" ::: "memory");
        __builtin_amdgcn_s_setprio(1);
        #pragma unroll
        for (int kk = 0; kk < 2; ++kk)
            #pragma unroll
            for (int mi = 0; mi < 4; ++mi)
                #pragma unroll
                for (int ni = 0; ni < 2; ++ni)
                    acc[mi][2 + ni] = __builtin_amdgcn_mfma_f32_16x16x32_bf16(
                        aF[kk][mi], b1F[kk][ni], acc[mi][2 + ni], 0, 0, 0);
        __builtin_amdgcn_s_setprio(0);
        __builtin_amdgcn_s_barrier();

        // ===== phase 3: quadrant (1,1); reads A rows {wr*128+64..127}; B dead 0..127 -> restage B0
        #pragma unroll
        for (int kk = 0; kk < 2; ++kk)
            #pragma unroll
            for (int mi = 0; mi < 4; ++mi)
                aF[kk][mi] = *(const bf16x8*)(Ab + aRowB + 8192 + mi * 2048 + swz[kk]);
        if (t + 2 < NT) stageBh(t + 2, 0);
        __builtin_amdgcn_s_barrier();
        asm volatile("s_waitcnt lgkmcnt(0)" ::: "memory");
        __builtin_amdgcn_s_setprio(1);
        #pragma unroll
        for (int kk = 0; kk < 2; ++kk)
            #pragma unroll
            for (int mi = 0; mi < 4; ++mi)
                #pragma unroll
                for (int ni = 0; ni < 2; ++ni)
                    acc[4 + mi][2 + ni] = __builtin_amdgcn_mfma_f32_16x16x32_bf16(
                        aF[kk][mi], b1F[kk][ni], acc[4 + mi][2 + ni], 0, 0, 0);
        __builtin_amdgcn_s_setprio(0);
        __builtin_amdgcn_s_barrier();

        // ===== phase 4: quadrant (1,0); no reads; restage A units 1,3 (dead after ph3)
        if (t + 2 < NT) { stageAu(t + 2, 1); stageAu(t + 2, 3); }
        if (t < NT - 2) asm volatile("s_waitcnt vmcnt(6)" ::: "memory");
        else            asm volatile("s_waitcnt vmcnt(0)" ::: "memory");
        __builtin_amdgcn_s_barrier();
        __builtin_amdgcn_s_setprio(1);
        #pragma unroll
        for (int kk = 0; kk < 2; ++kk)
            #pragma unroll
            for (int mi = 0; mi < 4; ++mi)
                #pragma unroll
                for (int ni = 0; ni < 2; ++ni)
                    acc[4 + mi][ni] = __builtin_amdgcn_mfma_f32_16x16x32_bf16(
                        aF[kk][mi], b0F[kk][ni], acc[4 + mi][ni], 0, 0, 0);
        __builtin_amdgcn_s_setprio(0);
        __builtin_amdgcn_s_barrier();
    }

    // ---- epilogue: bias add + store. C/D: col = lane&15, row = (lane>>4)*4 + r
    const int cl = lane & 15;
    const int r0 = (lane >> 4) * 4;
    float bv[4];
    #pragma unroll
    for (int nh = 0; nh < 2; ++nh)
        #pragma unroll
        for (int ni = 0; ni < 2; ++ni)
            bv[nh * 2 + ni] = bias[bcol + wc * 64 + nh * 32 + ni * 16 + cl];
    #pragma unroll
    for (int mh = 0; mh < 2; ++mh)
        #pragma unroll
        for (int mi = 0; mi < 4; ++mi) {
            const int row = brow + wr * 128 + mh * 64 + mi * 16 + r0;
            #pragma unroll
            for (int nh = 0; nh < 2; ++nh)
                #pragma unroll
                for (int ni = 0; ni < 2; ++ni) {
                    const int col = bcol + wc * 64 + nh * 32 + ni * 16 + cl;
                    float* op = out + (size_t)row * N_COLS + col;
                    const f32x4 v = acc[mh * 4 + mi][nh * 2 + ni];
                    const float bb = bv[nh * 2 + ni];
                    #pragma unroll
                    for (int r = 0; r < 4; ++r)
                        op[(size_t)r * N_COLS] = v[r] + bb;
                }
        }
}

// ---------------------------------------------------------------------------
extern "C" void kernel_launch(void* const* d_in, const int* in_sizes, int n_in,
                              void* d_out, int out_size, void* d_ws, size_t ws_size,
                              hipStream_t stream) {
    const float* x      = (const float*)d_in[0];
    const float* weight = (const float*)d_in[1];
    const float* bias   = (const float*)d_in[2];
    const float* lora_A = (const float*)d_in[3];
    const float* lora_B = (const float*)d_in[4];
    float* out = (float*)d_out;

    if (ws_size < XBF_BYTES + WBF_BYTES + LOW_BYTES + LBT_BYTES) return;

    char* ws = (char*)d_ws;
    bf16_t* Xbf  = (bf16_t*)ws;
    bf16_t* Wbf  = (bf16_t*)(ws + XBF_BYTES);
    bf16_t* lowb = (bf16_t*)(ws + XBF_BYTES + WBF_BYTES);
    bf16_t* lBt  = (bf16_t*)(ws + XBF_BYTES + WBF_BYTES + LOW_BYTES);

    hipMemsetAsync(lowb, 0, LOW_BYTES + LBT_BYTES, stream);

    convert_w_kernel<<<2048, 256, 0, stream>>>(weight, Wbf);
    make_lbt_kernel<<<64, 256, 0, stream>>>(lora_B, lBt);
    low_kernel<<<512, 256, 0, stream>>>(x, lora_A, Xbf, lowb);
    gemm_lora_kernel<<<512, 512, 0, stream>>>(Xbf, Wbf, lowb, lBt, bias, out);
}

// Round 4
// 346.787 us; speedup vs baseline: 1.5127x; 1.1133x over previous
//
#include <hip/hip_runtime.h>
#include <hip/hip_bf16.h>
#include <stdint.h>

typedef __bf16 bf16_t;
typedef __bf16 bf16x8 __attribute__((ext_vector_type(8)));
typedef float f32x4 __attribute__((ext_vector_type(4)));

#define M_ROWS 8192
#define N_COLS 4096
#define K_DIM  4096
#define KEXT   64
#define BM 256
#define BN 256
#define BK 64
#define NT 65   // 64 main K-tiles + 1 LoRA extension tile

// ws layout
#define XBF_BYTES (67108864ull)   // 8192*4096*2
#define WBF_BYTES (33554432ull)   // 4096*4096*2
#define LOW_BYTES (1048576ull)    // 8192*64*2
#define LBT_BYTES (2097152ull)    // 4*4096*64*2

__device__ __forceinline__ void gload16(const void* g, void* l) {
    __builtin_amdgcn_global_load_lds(
        (const __attribute__((address_space(1))) unsigned int*)g,
        (__attribute__((address_space(3))) unsigned int*)l, 16, 0, 0);
}

// ---------------------------------------------------------------------------
// Fused prep: [blocks 0..511]   Xbf = bf16(x); low = x @ lora_A (+zero pad)
//             [blocks 512..1535] Wbf = bf16(weight)
//             [blocks 1536..1599] lBt[b][n][r] = 2*lora_B[b][r][n] (+zero pad)
__global__ __launch_bounds__(256) void prep_kernel(
    const float* __restrict__ x, const float* __restrict__ lA,
    const float* __restrict__ lB, const float* __restrict__ weight,
    bf16_t* __restrict__ Xbf, bf16_t* __restrict__ Wbf,
    bf16_t* __restrict__ lowbf, bf16_t* __restrict__ lBt)
{
    const int blk = blockIdx.x;
    const int tid = threadIdx.x;

    if (blk < 512) {
        // ---- low + Xbf ----
        const int m0   = blk * 16;
        const int batch = m0 >> 11;
        const int rg   = tid >> 6;
        const int lane = tid & 63;
        const float* lAb = lA + (size_t)batch * (K_DIM * 16);

        f32x4 acc4[4][4];
        #pragma unroll
        for (int i = 0; i < 4; ++i)
            #pragma unroll
            for (int j = 0; j < 4; ++j)
                acc4[i][j] = (f32x4)0.0f;

        #pragma unroll 1
        for (int kc = 0; kc < 8; ++kc) {
            const int k0 = kc * 512 + lane * 8;
            float xs[4][8];
            #pragma unroll
            for (int rr = 0; rr < 4; ++rr) {
                const int m = m0 + rg * 4 + rr;
                const float* xp = x + (size_t)m * K_DIM + k0;
                const f32x4 a = *(const f32x4*)xp;
                const f32x4 b = *(const f32x4*)(xp + 4);
                bf16x8 v;
                v[0]=(bf16_t)a[0]; v[1]=(bf16_t)a[1]; v[2]=(bf16_t)a[2]; v[3]=(bf16_t)a[3];
                v[4]=(bf16_t)b[0]; v[5]=(bf16_t)b[1]; v[6]=(bf16_t)b[2]; v[7]=(bf16_t)b[3];
                *(bf16x8*)(Xbf + (size_t)m * K_DIM + k0) = v;
                xs[rr][0]=a[0]; xs[rr][1]=a[1]; xs[rr][2]=a[2]; xs[rr][3]=a[3];
                xs[rr][4]=b[0]; xs[rr][5]=b[1]; xs[rr][6]=b[2]; xs[rr][7]=b[3];
            }
            #pragma unroll
            for (int j = 0; j < 8; ++j) {
                const f32x4* lr = (const f32x4*)(lAb + (size_t)(k0 + j) * 16);
                const f32x4 l0 = lr[0], l1 = lr[1], l2 = lr[2], l3 = lr[3];
                #pragma unroll
                for (int rr = 0; rr < 4; ++rr) {
                    const float xv = xs[rr][j];
                    acc4[rr][0] += xv * l0;
                    acc4[rr][1] += xv * l1;
                    acc4[rr][2] += xv * l2;
                    acc4[rr][3] += xv * l3;
                }
            }
        }

        #pragma unroll
        for (int off = 32; off >= 1; off >>= 1) {
            #pragma unroll
            for (int rr = 0; rr < 4; ++rr)
                #pragma unroll
                for (int g = 0; g < 4; ++g)
                    #pragma unroll
                    for (int q = 0; q < 4; ++q)
                        acc4[rr][g][q] += __shfl_xor(acc4[rr][g][q], off, 64);
        }

        const int rr_w = lane >> 4, rw = lane & 15;
        float outv = 0.0f;
        #pragma unroll
        for (int rr = 0; rr < 4; ++rr)
            #pragma unroll
            for (int g = 0; g < 4; ++g)
                #pragma unroll
                for (int q = 0; q < 4; ++q)
                    if (rr == rr_w && (g * 4 + q) == rw) outv = acc4[rr][g][q];
        lowbf[(size_t)(m0 + rg * 4 + rr_w) * KEXT + rw] = (bf16_t)outv;

        // zero-fill cols 16..63 of the 16 rows (96 x 16B stores)
        if (tid < 96) {
            bf16x8 z;
            #pragma unroll
            for (int i = 0; i < 8; ++i) z[i] = (bf16_t)0.0f;
            const int row = m0 + tid / 6;
            const int c0  = 16 + (tid % 6) * 8;
            *(bf16x8*)(lowbf + (size_t)row * KEXT + c0) = z;
        }
    } else if (blk < 1536) {
        // ---- W f32 -> bf16 (1024 blocks x 256 thr x 8 iters x 8 elems) ----
        const long long i0 = (long long)(blk - 512) * 256 + tid;
        #pragma unroll 1
        for (int it = 0; it < 8; ++it) {
            const long long i = i0 + (long long)it * 262144;
            const f32x4* s = (const f32x4*)(weight + i * 8);
            const f32x4 a = s[0], b = s[1];
            bf16x8 v;
            v[0]=(bf16_t)a[0]; v[1]=(bf16_t)a[1]; v[2]=(bf16_t)a[2]; v[3]=(bf16_t)a[3];
            v[4]=(bf16_t)b[0]; v[5]=(bf16_t)b[1]; v[6]=(bf16_t)b[2]; v[7]=(bf16_t)b[3];
            *(bf16x8*)(Wbf + i * 8) = v;
        }
    } else {
        // ---- lBt + zero pad ----
        const int idx = (blk - 1536) * 256 + tid;   // 0..16383
        const int b = idx >> 12, n = idx & 4095;
        const float* src = lB + (size_t)b * (16 * N_COLS) + n;
        bf16_t* dst = lBt + ((size_t)b * N_COLS + n) * KEXT;
        bf16x8 v0, v1, z;
        #pragma unroll
        for (int r = 0; r < 8; ++r) {
            v0[r] = (bf16_t)(2.0f * src[(size_t)r * N_COLS]);
            v1[r] = (bf16_t)(2.0f * src[(size_t)(8 + r) * N_COLS]);
            z[r]  = (bf16_t)0.0f;
        }
        *(bf16x8*)(dst)      = v0;
        *(bf16x8*)(dst + 8)  = v1;
        #pragma unroll
        for (int c = 16; c < 64; c += 8)
            *(bf16x8*)(dst + c) = z;
    }
}

// ---------------------------------------------------------------------------
// GEMM helpers
__device__ __forceinline__ void read_a(bf16x8 (&d)[2][4], const char* base,
                                       int rowB, const int (&swz)[2]) {
    #pragma unroll
    for (int kk = 0; kk < 2; ++kk)
        #pragma unroll
        for (int mi = 0; mi < 4; ++mi)
            d[kk][mi] = *(const bf16x8*)(base + rowB + mi * 2048 + swz[kk]);
}
__device__ __forceinline__ void read_b(bf16x8 (&d)[2][2], const char* base,
                                       int rowB, const int (&swz)[2]) {
    #pragma unroll
    for (int kk = 0; kk < 2; ++kk)
        #pragma unroll
        for (int ni = 0; ni < 2; ++ni)
            d[kk][ni] = *(const bf16x8*)(base + rowB + ni * 2048 + swz[kk]);
}
template<int R0, int C0>
__device__ __forceinline__ void mfma_q(f32x4 (&acc)[8][4],
                                       const bf16x8 (&af)[2][4],
                                       const bf16x8 (&bf)[2][2]) {
    #pragma unroll
    for (int kk = 0; kk < 2; ++kk)
        #pragma unroll
        for (int mi = 0; mi < 4; ++mi)
            #pragma unroll
            for (int ni = 0; ni < 2; ++ni)
                acc[R0 + mi][C0 + ni] = __builtin_amdgcn_mfma_f32_16x16x32_bf16(
                    af[kk][mi], bf[kk][ni], acc[R0 + mi][C0 + ni], 0, 0, 0);
}

// ---------------------------------------------------------------------------
// 256x256 8-phase GEMM, read-ahead pipelined frag loads.
// Stage/vmcnt ledger identical to round-3 (verified): per iter t —
//   ph1 stageBh(t+1,1); ph2 stageAu(t+2,{0,2}); ph3 stageBh(t+2,0);
//   ph4 stageAu(t+2,{1,3}); vmcnt(6) at ph4 (vmcnt(0) from t=63).
// ds_read groups now issue INSIDE the preceding MFMA phase (post-lgkmcnt gate):
//   ph1: b1F(t) | ph2: a1F(t) | ph4 (post-vmcnt, tile t+1 resident): a0F(t+1), B0(t+1).
// WAR guards: each group drains at the next phase's lgkmcnt(0), which precedes
// (via barrier transitivity) the stage that overwrites its region.
__global__ __launch_bounds__(512, 1) void gemm_lora_kernel(
    const bf16_t* __restrict__ Xbf, const bf16_t* __restrict__ Wbf,
    const bf16_t* __restrict__ lowbf, const bf16_t* __restrict__ lBt,
    const float* __restrict__ bias, float* __restrict__ out)
{
    __shared__ __align__(16) char lds[131072];

    // XCD-aware bijective swizzle (512 % 8 == 0)
    int wg = blockIdx.x;
    const int cpx = gridDim.x >> 3;
    wg = (wg & 7) * cpx + (wg >> 3);

    const int nbn  = N_COLS / BN;            // 16
    const int brow = (wg / nbn) * BM;
    const int bcol = (wg % nbn) * BN;
    const int batch = brow >> 11;            // 256 | 2048

    const int tid  = threadIdx.x;
    const int lane = tid & 63;
    const int w    = tid >> 6;
    const int wr   = w >> 2;                 // 0..1 -> M half (128 rows)
    const int wc   = w & 3;                  // 0..3 -> N quarter (64 cols)

    // staging: one 64-row unit = 8192B = 512 thr x 16B
    const int srow   = tid >> 3;                                   // 0..63
    const int bphys  = (tid & 7) * 16;
    const int colOff = (bphys ^ ((srow & 7) << 4)) >> 1;           // elems

    const bf16_t* aSrc = Xbf + (size_t)(brow + srow) * K_DIM + colOff;
    const bf16_t* bSrc = Wbf + (size_t)(bcol + srow) * K_DIM + colOff;
    const bf16_t* aExt = lowbf + (size_t)(brow + srow) * KEXT + colOff;
    const bf16_t* bExt = lBt + ((size_t)batch * N_COLS + bcol + srow) * KEXT + colOff;

    auto stageAu = [&](int tau, int u) {
        char* dst = lds + (tau & 1) * 65536 + u * 8192 + tid * 16;
        if (tau < NT - 1) gload16(aSrc + (size_t)(u * 64) * K_DIM + tau * BK, dst);
        else              gload16(aExt + (size_t)(u * 64) * KEXT, dst);
    };
    auto stageBh = [&](int tau, int h) {
        char* dst = lds + (tau & 1) * 65536 + 32768 + h * 16384 + tid * 16;
        if (tau < NT - 1) {
            const bf16_t* s = bSrc + (size_t)(h * 128) * K_DIM + tau * BK;
            gload16(s, dst);
            gload16(s + (size_t)64 * K_DIM, dst + 8192);
        } else {
            const bf16_t* s = bExt + (size_t)(h * 128) * KEXT;
            gload16(s, dst);
            gload16(s + 64 * KEXT, dst + 8192);
        }
    };

    const int aRowB = (wr * 128 + (lane & 15)) * 128;
    const int bRowB = (wc * 64 + (lane & 15)) * 128;
    const int swz[2] = { (((lane >> 4) * 16) ^ ((lane & 7) << 4)),
                         ((64 + (lane >> 4) * 16) ^ ((lane & 7) << 4)) };

    f32x4 acc[8][4];
    #pragma unroll
    for (int i = 0; i < 8; ++i)
        #pragma unroll
        for (int j = 0; j < 4; ++j)
            acc[i][j] = (f32x4)0.0f;

    bf16x8 a0F[2][4], a1F[2][4], b1F[2][2], b0Fa[2][2], b0Fb[2][2];

    // ---- prologue: tile0 (8 loads) + tile1 {Au0,Au2,Bh0,Au1,Au3} (6 loads)
    stageAu(0, 0); stageAu(0, 1); stageAu(0, 2); stageAu(0, 3);
    stageBh(0, 0); stageBh(0, 1);
    stageAu(1, 0); stageAu(1, 2); stageBh(1, 0); stageAu(1, 1); stageAu(1, 3);
    asm volatile("s_waitcnt vmcnt(6)" ::: "memory");   // tile 0 landed
    __builtin_amdgcn_s_barrier();
    read_a(a0F, lds, aRowB, swz);
    read_b(b0Fa, lds + 32768, bRowB, swz);

#define ITER(T, CUR, NXT, B0C, B0N) do {                                      \
    const char* AbC = lds + (CUR) * 65536;                                    \
    const char* BbC = AbC + 32768;                                            \
    const char* AbN = lds + (NXT) * 65536;                                    \
    const char* BbN = AbN + 32768;                                            \
    /* ph1: MFMA q(0,0); issue b1F */                                         \
    if ((T) + 1 <= 64) stageBh((T) + 1, 1);                                   \
    __builtin_amdgcn_s_barrier();                                             \
    asm volatile("s_waitcnt lgkmcnt(0)" ::: "memory");                        \
    __builtin_amdgcn_s_setprio(1);                                            \
    read_b(b1F, BbC + 4096, bRowB, swz);                                      \
    mfma_q<0, 0>(acc, a0F, B0C);                                              \
    __builtin_amdgcn_s_setprio(0);                                            \
    __builtin_amdgcn_s_barrier();                                             \
    /* ph2: MFMA q(0,1); issue a1F */                                         \
    if ((T) + 2 <= 64) { stageAu((T) + 2, 0); stageAu((T) + 2, 2); }          \
    __builtin_amdgcn_s_barrier();                                             \
    asm volatile("s_waitcnt lgkmcnt(0)" ::: "memory");                        \
    __builtin_amdgcn_s_setprio(1);                                            \
    read_a(a1F, AbC + 8192, aRowB, swz);                                      \
    mfma_q<0, 2>(acc, a0F, b1F);                                              \
    __builtin_amdgcn_s_setprio(0);                                            \
    __builtin_amdgcn_s_barrier();                                             \
    /* ph3: MFMA q(1,1); no reads (lgkm gates a1F + WAR) */                   \
    if ((T) + 2 <= 64) stageBh((T) + 2, 0);                                   \
    __builtin_amdgcn_s_barrier();                                             \
    asm volatile("s_waitcnt lgkmcnt(0)" ::: "memory");                        \
    __builtin_amdgcn_s_setprio(1);                                            \
    mfma_q<4, 2>(acc, a1F, b1F);                                              \
    __builtin_amdgcn_s_setprio(0);                                            \
    __builtin_amdgcn_s_barrier();                                             \
    /* ph4: vmcnt gate -> tile T+1 resident; issue a0F/B0 of T+1; MFMA q(1,0) */ \
    if ((T) + 2 <= 64) { stageAu((T) + 2, 1); stageAu((T) + 2, 3); }          \
    if ((T) < 63) { asm volatile("s_waitcnt vmcnt(6)" ::: "memory"); }        \
    else          { asm volatile("s_waitcnt vmcnt(0)" ::: "memory"); }        \
    __builtin_amdgcn_s_barrier();                                             \
    __builtin_amdgcn_s_setprio(1);                                            \
    if ((T) < 64) { read_a(a0F, AbN, aRowB, swz);                             \
                    read_b(B0N, BbN, bRowB, swz); }                           \
    mfma_q<4, 0>(acc, a1F, B0C);                                              \
    __builtin_amdgcn_s_setprio(0);                                            \
    __builtin_amdgcn_s_barrier();                                             \
} while (0)

    #pragma unroll 1
    for (int t = 0; t < 64; t += 2) {
        ITER(t,     0, 1, b0Fa, b0Fb);
        ITER(t + 1, 1, 0, b0Fb, b0Fa);
    }
    ITER(64, 0, 1, b0Fa, b0Fb);   // ext tile; all stages/reads compile out
#undef ITER

    // ---- epilogue: bias add + store. C/D: col = lane&15, row = (lane>>4)*4+r
    const int cl = lane & 15;
    const int r0 = (lane >> 4) * 4;
    float bv[4];
    #pragma unroll
    for (int nh = 0; nh < 2; ++nh)
        #pragma unroll
        for (int ni = 0; ni < 2; ++ni)
            bv[nh * 2 + ni] = bias[bcol + wc * 64 + nh * 32 + ni * 16 + cl];
    #pragma unroll
    for (int mh = 0; mh < 2; ++mh)
        #pragma unroll
        for (int mi = 0; mi < 4; ++mi) {
            const int row = brow + wr * 128 + mh * 64 + mi * 16 + r0;
            #pragma unroll
            for (int nh = 0; nh < 2; ++nh)
                #pragma unroll
                for (int ni = 0; ni < 2; ++ni) {
                    const int col = bcol + wc * 64 + nh * 32 + ni * 16 + cl;
                    float* op = out + (size_t)row * N_COLS + col;
                    const f32x4 v = acc[mh * 4 + mi][nh * 2 + ni];
                    const float bb = bv[nh * 2 + ni];
                    #pragma unroll
                    for (int r = 0; r < 4; ++r)
                        op[(size_t)r * N_COLS] = v[r] + bb;
                }
        }
}

// ---------------------------------------------------------------------------
extern "C" void kernel_launch(void* const* d_in, const int* in_sizes, int n_in,
                              void* d_out, int out_size, void* d_ws, size_t ws_size,
                              hipStream_t stream) {
    const float* x      = (const float*)d_in[0];
    const float* weight = (const float*)d_in[1];
    const float* bias   = (const float*)d_in[2];
    const float* lora_A = (const float*)d_in[3];
    const float* lora_B = (const float*)d_in[4];
    float* out = (float*)d_out;

    if (ws_size < XBF_BYTES + WBF_BYTES + LOW_BYTES + LBT_BYTES) return;

    char* ws = (char*)d_ws;
    bf16_t* Xbf  = (bf16_t*)ws;
    bf16_t* Wbf  = (bf16_t*)(ws + XBF_BYTES);
    bf16_t* lowb = (bf16_t*)(ws + XBF_BYTES + WBF_BYTES);
    bf16_t* lBt  = (bf16_t*)(ws + XBF_BYTES + WBF_BYTES + LOW_BYTES);

    prep_kernel<<<1600, 256, 0, stream>>>(x, lora_A, lora_B, weight,
                                          Xbf, Wbf, lowb, lBt);
    gemm_lora_kernel<<<512, 512, 0, stream>>>(Xbf, Wbf, lowb, lBt, bias, out);
}

// Round 5
// 322.510 us; speedup vs baseline: 1.6266x; 1.0753x over previous
//
#include <hip/hip_runtime.h>
#include <hip/hip_bf16.h>
#include <stdint.h>

typedef __bf16 bf16_t;
typedef __bf16 bf16x8 __attribute__((ext_vector_type(8)));
typedef float f32x4 __attribute__((ext_vector_type(4)));

#define M_ROWS 8192
#define N_COLS 4096
#define K_DIM  4096
#define KEXT   64
#define BM 256
#define BN 256
#define BK 64
#define NT 65   // 64 main K-tiles + 1 LoRA extension tile

// ws layout
#define XBF_BYTES (67108864ull)   // 8192*4096*2
#define WBF_BYTES (33554432ull)   // 4096*4096*2
#define LOW_BYTES (1048576ull)    // 8192*64*2
#define LBT_BYTES (2097152ull)    // 4*4096*64*2
#define LAT_BYTES (524288ull)     // 4*16*4096*2

__device__ __forceinline__ void gload16(const void* g, void* l) {
    __builtin_amdgcn_global_load_lds(
        (const __attribute__((address_space(1))) unsigned int*)g,
        (__attribute__((address_space(3))) unsigned int*)l, 16, 0, 0);
}

// ---------------------------------------------------------------------------
// Streaming prep (all coalesced):
//   [0..511]     Xbf = bf16(x)              (512 blk x 256 thr x 32 it x 8)
//   [512..1535]  Wbf = bf16(weight)         (1024 blk x 256 thr x 8 it x 8)
//   [1536..1599] lBt[b][n][r] = 2*lora_B[b][r][n] (+zero pad r=16..63)
//   [1600..1663] lAT[b][c][k] = bf16(lora_A[b][k][c])
__global__ __launch_bounds__(256) void prep_kernel(
    const float* __restrict__ x, const float* __restrict__ lA,
    const float* __restrict__ lB, const float* __restrict__ weight,
    bf16_t* __restrict__ Xbf, bf16_t* __restrict__ Wbf,
    bf16_t* __restrict__ lBt, bf16_t* __restrict__ lAT)
{
    const int blk = blockIdx.x;
    const int tid = threadIdx.x;

    if (blk < 512) {
        const long long i0 = (long long)blk * 256 + tid;
        #pragma unroll 1
        for (int it = 0; it < 32; ++it) {
            const long long i = i0 + (long long)it * 131072;
            const f32x4* s = (const f32x4*)(x + i * 8);
            const f32x4 a = s[0], b = s[1];
            bf16x8 v;
            v[0]=(bf16_t)a[0]; v[1]=(bf16_t)a[1]; v[2]=(bf16_t)a[2]; v[3]=(bf16_t)a[3];
            v[4]=(bf16_t)b[0]; v[5]=(bf16_t)b[1]; v[6]=(bf16_t)b[2]; v[7]=(bf16_t)b[3];
            *(bf16x8*)(Xbf + i * 8) = v;
        }
    } else if (blk < 1536) {
        const long long i0 = (long long)(blk - 512) * 256 + tid;
        #pragma unroll 1
        for (int it = 0; it < 8; ++it) {
            const long long i = i0 + (long long)it * 262144;
            const f32x4* s = (const f32x4*)(weight + i * 8);
            const f32x4 a = s[0], b = s[1];
            bf16x8 v;
            v[0]=(bf16_t)a[0]; v[1]=(bf16_t)a[1]; v[2]=(bf16_t)a[2]; v[3]=(bf16_t)a[3];
            v[4]=(bf16_t)b[0]; v[5]=(bf16_t)b[1]; v[6]=(bf16_t)b[2]; v[7]=(bf16_t)b[3];
            *(bf16x8*)(Wbf + i * 8) = v;
        }
    } else if (blk < 1600) {
        const int idx = (blk - 1536) * 256 + tid;   // 0..16383
        const int b = idx >> 12, n = idx & 4095;
        const float* src = lB + (size_t)b * (16 * N_COLS) + n;
        bf16_t* dst = lBt + ((size_t)b * N_COLS + n) * KEXT;
        bf16x8 v0, v1, z;
        #pragma unroll
        for (int r = 0; r < 8; ++r) {
            v0[r] = (bf16_t)(2.0f * src[(size_t)r * N_COLS]);
            v1[r] = (bf16_t)(2.0f * src[(size_t)(8 + r) * N_COLS]);
            z[r]  = (bf16_t)0.0f;
        }
        *(bf16x8*)(dst)     = v0;
        *(bf16x8*)(dst + 8) = v1;
        #pragma unroll
        for (int c = 16; c < 64; c += 8)
            *(bf16x8*)(dst + c) = z;
    } else {
        // lAT: block q = one (batch, col); thread covers 16 consecutive k
        const int q = blk - 1600;              // 0..63
        const int b = q >> 4, c = q & 15;
        const float* src = lA + (size_t)b * (K_DIM * 16) + c;
        bf16_t* dst = lAT + ((size_t)b * 16 + c) * K_DIM + tid * 16;
        bf16x8 v0, v1;
        #pragma unroll
        for (int j = 0; j < 8; ++j) {
            v0[j] = (bf16_t)src[(size_t)(tid * 16 + j) * 16];
            v1[j] = (bf16_t)src[(size_t)(tid * 16 + 8 + j) * 16];
        }
        *(bf16x8*)(dst)     = v0;
        *(bf16x8*)(dst + 8) = v1;
    }
}

// ---------------------------------------------------------------------------
// low = Xbf @ lora_A via MFMA. 256 blocks x 32 rows; 4 waves =
// (rowg 0..1 -> 16 rows) x (khalf 0..1 -> K half). 2 interleaved acc chains.
// Writes low[32][16] bf16 (+zero pad cols 16..63).
__global__ __launch_bounds__(256) void lowg_kernel(
    const bf16_t* __restrict__ Xbf, const bf16_t* __restrict__ lAT,
    bf16_t* __restrict__ lowbf)
{
    __shared__ f32x4 lsum[128];
    const int tid  = threadIdx.x;
    const int w    = tid >> 6;
    const int lane = tid & 63;
    const int rowg = w >> 1, khalf = w & 1;
    const int m0   = blockIdx.x * 32;
    const int batch = m0 >> 11;
    const int r16  = lane & 15;
    const int kg   = lane >> 4;

    const bf16_t* aB = Xbf + (size_t)(m0 + rowg * 16 + r16) * K_DIM + khalf * 2048 + kg * 8;
    const bf16_t* bB = lAT + ((size_t)batch * 16 + r16) * K_DIM + khalf * 2048 + kg * 8;

    f32x4 acc0 = (f32x4)0.0f, acc1 = (f32x4)0.0f;
    #pragma unroll 4
    for (int ks = 0; ks < 32; ++ks) {
        acc0 = __builtin_amdgcn_mfma_f32_16x16x32_bf16(
            *(const bf16x8*)(aB + ks * 64), *(const bf16x8*)(bB + ks * 64), acc0, 0, 0, 0);
        acc1 = __builtin_amdgcn_mfma_f32_16x16x32_bf16(
            *(const bf16x8*)(aB + ks * 64 + 32), *(const bf16x8*)(bB + ks * 64 + 32), acc1, 0, 0, 0);
    }
    f32x4 s = acc0 + acc1;
    if (khalf == 1) lsum[rowg * 64 + lane] = s;
    __syncthreads();
    if (khalf == 0) {
        s += lsum[rowg * 64 + lane];
        // D layout: col(=r index) = lane&15, row = (lane>>4)*4 + ri
        const int m = m0 + rowg * 16 + kg * 4;
        #pragma unroll
        for (int ri = 0; ri < 4; ++ri)
            lowbf[(size_t)(m + ri) * KEXT + r16] = (bf16_t)s[ri];
    }
    // zero pad cols 16..63 of rows m0..m0+31 (32 rows x 6 x 8 elems)
    if (tid < 192) {
        bf16x8 z;
        #pragma unroll
        for (int i = 0; i < 8; ++i) z[i] = (bf16_t)0.0f;
        const int row = m0 + tid / 6;
        const int c0  = 16 + (tid % 6) * 8;
        *(bf16x8*)(lowbf + (size_t)row * KEXT + c0) = z;
    }
}

// ---------------------------------------------------------------------------
// GEMM helpers
__device__ __forceinline__ void read_a(bf16x8 (&d)[2][4], const char* base,
                                       int rowB, const int (&swz)[2]) {
    #pragma unroll
    for (int kk = 0; kk < 2; ++kk)
        #pragma unroll
        for (int mi = 0; mi < 4; ++mi)
            d[kk][mi] = *(const bf16x8*)(base + rowB + mi * 2048 + swz[kk]);
}
__device__ __forceinline__ void read_b(bf16x8 (&d)[2][2], const char* base,
                                       int rowB, const int (&swz)[2]) {
    #pragma unroll
    for (int kk = 0; kk < 2; ++kk)
        #pragma unroll
        for (int ni = 0; ni < 2; ++ni)
            d[kk][ni] = *(const bf16x8*)(base + rowB + ni * 2048 + swz[kk]);
}
template<int R0, int C0>
__device__ __forceinline__ void mfma_q(f32x4 (&acc)[8][4],
                                       const bf16x8 (&af)[2][4],
                                       const bf16x8 (&bf)[2][2]) {
    #pragma unroll
    for (int kk = 0; kk < 2; ++kk)
        #pragma unroll
        for (int mi = 0; mi < 4; ++mi)
            #pragma unroll
            for (int ni = 0; ni < 2; ++ni)
                acc[R0 + mi][C0 + ni] = __builtin_amdgcn_mfma_f32_16x16x32_bf16(
                    af[kk][mi], bf[kk][ni], acc[R0 + mi][C0 + ni], 0, 0, 0);
}

// ---------------------------------------------------------------------------
// 256x256 8-phase GEMM, read-ahead pipelined frag loads (round-4 ledger,
// verified). Reads issued after the lgkmcnt gate but BEFORE setprio(1).
__global__ __launch_bounds__(512, 1) void gemm_lora_kernel(
    const bf16_t* __restrict__ Xbf, const bf16_t* __restrict__ Wbf,
    const bf16_t* __restrict__ lowbf, const bf16_t* __restrict__ lBt,
    const float* __restrict__ bias, float* __restrict__ out)
{
    __shared__ __align__(16) char lds[131072];

    int wg = blockIdx.x;
    const int cpx = gridDim.x >> 3;
    wg = (wg & 7) * cpx + (wg >> 3);

    const int nbn  = N_COLS / BN;            // 16
    const int brow = (wg / nbn) * BM;
    const int bcol = (wg % nbn) * BN;
    const int batch = brow >> 11;

    const int tid  = threadIdx.x;
    const int lane = tid & 63;
    const int w    = tid >> 6;
    const int wr   = w >> 2;
    const int wc   = w & 3;

    const int srow   = tid >> 3;
    const int bphys  = (tid & 7) * 16;
    const int colOff = (bphys ^ ((srow & 7) << 4)) >> 1;

    const bf16_t* aSrc = Xbf + (size_t)(brow + srow) * K_DIM + colOff;
    const bf16_t* bSrc = Wbf + (size_t)(bcol + srow) * K_DIM + colOff;
    const bf16_t* aExt = lowbf + (size_t)(brow + srow) * KEXT + colOff;
    const bf16_t* bExt = lBt + ((size_t)batch * N_COLS + bcol + srow) * KEXT + colOff;

    auto stageAu = [&](int tau, int u) {
        char* dst = lds + (tau & 1) * 65536 + u * 8192 + tid * 16;
        if (tau < NT - 1) gload16(aSrc + (size_t)(u * 64) * K_DIM + tau * BK, dst);
        else              gload16(aExt + (size_t)(u * 64) * KEXT, dst);
    };
    auto stageBh = [&](int tau, int h) {
        char* dst = lds + (tau & 1) * 65536 + 32768 + h * 16384 + tid * 16;
        if (tau < NT - 1) {
            const bf16_t* s = bSrc + (size_t)(h * 128) * K_DIM + tau * BK;
            gload16(s, dst);
            gload16(s + (size_t)64 * K_DIM, dst + 8192);
        } else {
            const bf16_t* s = bExt + (size_t)(h * 128) * KEXT;
            gload16(s, dst);
            gload16(s + 64 * KEXT, dst + 8192);
        }
    };

    const int aRowB = (wr * 128 + (lane & 15)) * 128;
    const int bRowB = (wc * 64 + (lane & 15)) * 128;
    const int swz[2] = { (((lane >> 4) * 16) ^ ((lane & 7) << 4)),
                         ((64 + (lane >> 4) * 16) ^ ((lane & 7) << 4)) };

    f32x4 acc[8][4];
    #pragma unroll
    for (int i = 0; i < 8; ++i)
        #pragma unroll
        for (int j = 0; j < 4; ++j)
            acc[i][j] = (f32x4)0.0f;

    bf16x8 a0F[2][4], a1F[2][4], b1F[2][2], b0Fa[2][2], b0Fb[2][2];

    stageAu(0, 0); stageAu(0, 1); stageAu(0, 2); stageAu(0, 3);
    stageBh(0, 0); stageBh(0, 1);
    stageAu(1, 0); stageAu(1, 2); stageBh(1, 0); stageAu(1, 1); stageAu(1, 3);
    asm volatile("s_waitcnt vmcnt(6)" ::: "memory");
    __builtin_amdgcn_s_barrier();
    read_a(a0F, lds, aRowB, swz);
    read_b(b0Fa, lds + 32768, bRowB, swz);

#define ITER(T, CUR, NXT, B0C, B0N) do {                                      \
    const char* AbC = lds + (CUR) * 65536;                                    \
    const char* BbC = AbC + 32768;                                            \
    const char* AbN = lds + (NXT) * 65536;                                    \
    const char* BbN = AbN + 32768;                                            \
    /* ph1: MFMA q(0,0); issue b1F */                                         \
    if ((T) + 1 <= 64) stageBh((T) + 1, 1);                                   \
    __builtin_amdgcn_s_barrier();                                             \
    asm volatile("s_waitcnt lgkmcnt(0)" ::: "memory");                        \
    read_b(b1F, BbC + 4096, bRowB, swz);                                      \
    __builtin_amdgcn_s_setprio(1);                                            \
    mfma_q<0, 0>(acc, a0F, B0C);                                              \
    __builtin_amdgcn_s_setprio(0);                                            \
    __builtin_amdgcn_s_barrier();                                             \
    /* ph2: MFMA q(0,1); issue a1F */                                         \
    if ((T) + 2 <= 64) { stageAu((T) + 2, 0); stageAu((T) + 2, 2); }          \
    __builtin_amdgcn_s_barrier();                                             \
    asm volatile("s_waitcnt lgkmcnt(0)" ::: "memory");                        \
    read_a(a1F, AbC + 8192, aRowB, swz);                                      \
    __builtin_amdgcn_s_setprio(1);                                            \
    mfma_q<0, 2>(acc, a0F, b1F);                                              \
    __builtin_amdgcn_s_setprio(0);                                            \
    __builtin_amdgcn_s_barrier();                                             \
    /* ph3: MFMA q(1,1) */                                                    \
    if ((T) + 2 <= 64) stageBh((T) + 2, 0);                                   \
    __builtin_amdgcn_s_barrier();                                             \
    asm volatile("s_waitcnt lgkmcnt(0)" ::: "memory");                        \
    __builtin_amdgcn_s_setprio(1);                                            \
    mfma_q<4, 2>(acc, a1F, b1F);                                              \
    __builtin_amdgcn_s_setprio(0);                                            \
    __builtin_amdgcn_s_barrier();                                             \
    /* ph4: vmcnt gate -> tile T+1 resident; issue a0F/B0 of T+1 */           \
    if ((T) + 2 <= 64) { stageAu((T) + 2, 1); stageAu((T) + 2, 3); }          \
    if ((T) < 63) { asm volatile("s_waitcnt vmcnt(6)" ::: "memory"); }        \
    else          { asm volatile("s_waitcnt vmcnt(0)" ::: "memory"); }        \
    __builtin_amdgcn_s_barrier();                                             \
    if ((T) < 64) { read_a(a0F, AbN, aRowB, swz);                             \
                    read_b(B0N, BbN, bRowB, swz); }                           \
    __builtin_amdgcn_s_setprio(1);                                            \
    mfma_q<4, 0>(acc, a1F, B0C);                                              \
    __builtin_amdgcn_s_setprio(0);                                            \
    __builtin_amdgcn_s_barrier();                                             \
} while (0)

    #pragma unroll 1
    for (int t = 0; t < 64; t += 2) {
        ITER(t,     0, 1, b0Fa, b0Fb);
        ITER(t + 1, 1, 0, b0Fb, b0Fa);
    }
    ITER(64, 0, 1, b0Fa, b0Fb);
#undef ITER

    const int cl = lane & 15;
    const int r0 = (lane >> 4) * 4;
    float bv[4];
    #pragma unroll
    for (int nh = 0; nh < 2; ++nh)
        #pragma unroll
        for (int ni = 0; ni < 2; ++ni)
            bv[nh * 2 + ni] = bias[bcol + wc * 64 + nh * 32 + ni * 16 + cl];
    #pragma unroll
    for (int mh = 0; mh < 2; ++mh)
        #pragma unroll
        for (int mi = 0; mi < 4; ++mi) {
            const int row = brow + wr * 128 + mh * 64 + mi * 16 + r0;
            #pragma unroll
            for (int nh = 0; nh < 2; ++nh)
                #pragma unroll
                for (int ni = 0; ni < 2; ++ni) {
                    const int col = bcol + wc * 64 + nh * 32 + ni * 16 + cl;
                    float* op = out + (size_t)row * N_COLS + col;
                    const f32x4 v = acc[mh * 4 + mi][nh * 2 + ni];
                    const float bb = bv[nh * 2 + ni];
                    #pragma unroll
                    for (int r = 0; r < 4; ++r)
                        op[(size_t)r * N_COLS] = v[r] + bb;
                }
        }
}

// ---------------------------------------------------------------------------
extern "C" void kernel_launch(void* const* d_in, const int* in_sizes, int n_in,
                              void* d_out, int out_size, void* d_ws, size_t ws_size,
                              hipStream_t stream) {
    const float* x      = (const float*)d_in[0];
    const float* weight = (const float*)d_in[1];
    const float* bias   = (const float*)d_in[2];
    const float* lora_A = (const float*)d_in[3];
    const float* lora_B = (const float*)d_in[4];
    float* out = (float*)d_out;

    if (ws_size < XBF_BYTES + WBF_BYTES + LOW_BYTES + LBT_BYTES + LAT_BYTES) return;

    char* ws = (char*)d_ws;
    bf16_t* Xbf  = (bf16_t*)ws;
    bf16_t* Wbf  = (bf16_t*)(ws + XBF_BYTES);
    bf16_t* lowb = (bf16_t*)(ws + XBF_BYTES + WBF_BYTES);
    bf16_t* lBt  = (bf16_t*)(ws + XBF_BYTES + WBF_BYTES + LOW_BYTES);
    bf16_t* lAT  = (bf16_t*)(ws + XBF_BYTES + WBF_BYTES + LOW_BYTES + LBT_BYTES);

    prep_kernel<<<1664, 256, 0, stream>>>(x, lora_A, lora_B, weight,
                                          Xbf, Wbf, lBt, lAT);
    lowg_kernel<<<256, 256, 0, stream>>>(Xbf, lAT, lowb);
    gemm_lora_kernel<<<512, 512, 0, stream>>>(Xbf, Wbf, lowb, lBt, bias, out);
}